// Round 2
// baseline (245.613 us; speedup 1.0000x reference)
//
#include <hip/hip_runtime.h>
#include <math.h>

#define TPB 256
constexpr int kS = 7;
constexpr int kB = 2;
constexpr int kC = 20;
constexpr int kT = 32;
constexpr int kCH = kB * 5 + kC;      // 30 channels
constexpr int kCells = kS * kS;       // 49
constexpr int kImgF = kCells * kCH;   // 1470 floats per image
constexpr int IMGS = 4;               // images per block (23520 B LDS -> 6 blocks/CU)

// Block-wide sum reduction (result valid on thread 0 only).
__device__ __forceinline__ float block_reduce(float v, float* red) {
    #pragma unroll
    for (int off = 32; off > 0; off >>= 1)
        v += __shfl_down(v, off, 64);
    const int lane = threadIdx.x & 63;
    const int wave = threadIdx.x >> 6;
    if (lane == 0) red[wave] = v;
    __syncthreads();
    float s = 0.0f;
    if (threadIdx.x == 0) {
        #pragma unroll
        for (int w = 0; w < TPB / 64; w++) s += red[w];
    }
    return s;
}

// Fused: stream IMGS images -> LDS (noobj conf^2 accumulated from registers
// during the load), per-target terms from LDS, block reduce, device atomic
// accumulate, last block writes the mean.
__global__ __launch_bounds__(TPB) void yolo_fused(
    const float* __restrict__ outputs,
    const float4* __restrict__ tboxes,
    const int* __restrict__ tlabels,
    float* __restrict__ out,
    float* __restrict__ accum,         // d_ws+0, zeroed by memset node
    unsigned* __restrict__ counter,    // d_ws+4, zeroed by memset node
    int n, int nblocks, float invn)
{
    __shared__ float smem[IMGS * kImgF];   // 23520 B
    __shared__ float red[TPB / 64];
    const int tid = threadIdx.x;
    const int img0 = blockIdx.x * IMGS;
    const int nimg = min(IMGS, n - img0);

    float local = 0.0f;
    const float kno = 0.5f / (float)(2 * kCells);   // LAMBDA_NOOBJ * (1/98)

    // ---- Stage outputs into LDS, coalesced float4; noobj conf^2 from regs ----
    if (nimg == IMGS) {
        const float4* src = reinterpret_cast<const float4*>(outputs + (size_t)img0 * kImgF);
        float4* dst = reinterpret_cast<float4*>(smem);
        constexpr int NV4 = IMGS * kImgF / 4;       // 1470
        #pragma unroll
        for (int i = 0; i < (NV4 + TPB - 1) / TPB; i++) {
            const int idx = tid + i * TPB;
            if (idx < NV4) {
                const float4 v = src[idx];
                dst[idx] = v;
                // channel of v.x: (4*idx) % 30. Conf pair (ch 8,9) never
                // straddles a float4 (cell stride 30 == 2 mod 4).
                const int base = (4 * idx) % 30;
                if (base == 8)      local += kno * (v.x * v.x + v.y * v.y);
                else if (base == 6) local += kno * (v.z * v.z + v.w * v.w);
            }
        }
    } else {
        // tail (never hit at N=16384): scalar, correct but slow
        const float* srcf = outputs + (size_t)img0 * kImgF;
        const int tot = nimg * kImgF;
        for (int i = tid; i < tot; i += TPB) {
            const float v = srcf[i];
            smem[i] = v;
            const int ch = i % kCH;
            if (ch == 8 || ch == 9) local += kno * v * v;
        }
    }
    __syncthreads();

    // ---- per-target terms: thread tid -> target (tid&31) of image (tid>>5) ----
    if (tid < nimg * kT) {
        const int sub = tid >> 5;
        const float4 tb = tboxes[(size_t)img0 * kT + tid];
        const int lab = tlabels[(size_t)img0 * kT + tid];
        const float cellf = 1.0f / 7.0f;
        const float tx = tb.x, ty = tb.y, tw = tb.z, th = tb.w;

        int gxi = (int)(tx / cellf); gxi = min(max(gxi, 0), kS - 1);
        int gyi = (int)(ty / cellf); gyi = min(max(gyi, 0), kS - 1);
        const float ox = (tx - (float)gxi * cellf) / cellf;
        const float oy = (ty - (float)gyi * cellf) / cellf;
        const float* cellp = &smem[sub * kImgF + (gyi * kS + gxi) * kCH];

        const float t_x1 = tx - tw * 0.5f, t_x2 = tx + tw * 0.5f;
        const float t_y1 = ty - th * 0.5f, t_y2 = ty + th * 0.5f;
        const float tarea = tw * th;
        float ious[2], bxs[2], bys[2], bws[2], bhs[2];
        #pragma unroll
        for (int b = 0; b < 2; b++) {
            const float x = cellp[4 * b + 0], y = cellp[4 * b + 1];
            const float w = cellp[4 * b + 2], h = cellp[4 * b + 3];
            const float px = (x + (float)gxi) * cellf;
            const float py = (y + (float)gyi) * cellf;
            const float x21 = px - w * 0.5f, x22 = px + w * 0.5f;
            const float y21 = py - h * 0.5f, y22 = py + h * 0.5f;
            const float iw = fmaxf(fminf(t_x2, x22) - fmaxf(t_x1, x21), 0.0f);
            const float ih = fmaxf(fminf(t_y2, y22) - fmaxf(t_y1, y21), 0.0f);
            const float inter = iw * ih;
            const float uni = tarea + w * h - inter;
            ious[b] = inter / fmaxf(uni, 1e-6f);
            bxs[b] = px; bys[b] = py; bws[b] = w; bhs[b] = h;
        }
        // jnp.argmax picks the FIRST max on ties -> strict '>' for index 1
        const int best = (ious[1] > ious[0]) ? 1 : 0;

        const float pw = fmaxf(bws[best], 1e-6f), ph = fmaxf(bhs[best], 1e-6f);
        const float twc = fmaxf(tw, 1e-6f), thc = fmaxf(th, 1e-6f);
        const float dx = bxs[best] - ox, dy = bys[best] - oy;
        const float dw = sqrtf(pw) - sqrtf(twc), dh = sqrtf(ph) - sqrtf(thc);
        const float box_loss = dx * dx + dy * dy + dw * dw + dh * dh;

        const float dconf = cellp[8 + best] - 1.0f;
        const float obj_loss = dconf * dconf;

        // class loss: mean over C of (softmax - onehot)^2
        float m = cellp[10];
        #pragma unroll
        for (int c = 1; c < kC; c++) m = fmaxf(m, cellp[10 + c]);
        float es[kC];
        float ssum = 0.0f;
        #pragma unroll
        for (int c = 0; c < kC; c++) { es[c] = __expf(cellp[10 + c] - m); ssum += es[c]; }
        const float inv = 1.0f / ssum;
        float cl = 0.0f;
        #pragma unroll
        for (int c = 0; c < kC; c++) {
            const float d = es[c] * inv - (c == lab ? 1.0f : 0.0f);
            cl += d * d;
        }

        local += 5.0f * box_loss + obj_loss + cl * (1.0f / (float)kC);
    }

    const float bsum = block_reduce(local, red);

    // ---- device-scope accumulate + last-block finalize ----
    if (tid == 0) {
        atomicAdd(accum, bsum);
        __threadfence();                       // release: accum add visible before counter inc
        const unsigned old = atomicAdd(counter, 1u);
        if (old == (unsigned)(nblocks - 1)) {
            __threadfence();                   // acquire side
            const float total = atomicAdd(accum, 0.0f);   // coherent read via RMW
            out[0] = total * invn;
        }
    }
}

extern "C" void kernel_launch(void* const* d_in, const int* in_sizes, int n_in,
                              void* d_out, int out_size, void* d_ws, size_t ws_size,
                              hipStream_t stream)
{
    const float* outputs = (const float*)d_in[0];
    const float4* tboxes = (const float4*)d_in[1];
    const int* tlabels = (const int*)d_in[2];
    float* out = (float*)d_out;
    float* accum = (float*)d_ws;
    unsigned* counter = (unsigned*)((char*)d_ws + 4);

    const int n = in_sizes[0] / kImgF;                 // 16384
    const int nblocks = (n + IMGS - 1) / IMGS;         // 4096

    hipMemsetAsync(d_ws, 0, 8, stream);                // zero accum + counter (graph-legal)
    yolo_fused<<<nblocks, TPB, 0, stream>>>(outputs, tboxes, tlabels, out,
                                            accum, counter, n, nblocks,
                                            1.0f / (float)n);
}

// Round 3
// 157.800 us; speedup vs baseline: 1.5565x; 1.5565x over previous
//
#include <hip/hip_runtime.h>
#include <math.h>

#define TPB 256
constexpr int kS = 7;
constexpr int kB = 2;
constexpr int kC = 20;
constexpr int kT = 32;
constexpr int kCH = kB * 5 + kC;      // 30 channels
constexpr int kCells = kS * kS;       // 49
constexpr int kImgF = kCells * kCH;   // 1470 floats per image
constexpr int IMGS = 4;               // images per block (23520 B LDS -> 6 blocks/CU)

// Block-wide sum reduction (result valid on thread 0 only).
__device__ __forceinline__ float block_reduce(float v, float* red) {
    #pragma unroll
    for (int off = 32; off > 0; off >>= 1)
        v += __shfl_down(v, off, 64);
    const int lane = threadIdx.x & 63;
    const int wave = threadIdx.x >> 6;
    if (lane == 0) red[wave] = v;
    __syncthreads();
    float s = 0.0f;
    if (threadIdx.x == 0) {
        #pragma unroll
        for (int w = 0; w < TPB / 64; w++) s += red[w];
    }
    return s;
}

// Stage 1: each block streams IMGS images into LDS (noobj conf^2 accumulated
// from registers during the load), computes per-target terms, writes ONE
// partial per block. No atomics anywhere (same-line atomic RMW across 4096
// blocks serialized at ~15ns each in R2 -> 150us kernel; two-stage is cheap).
__global__ __launch_bounds__(TPB) void yolo_stage1(
    const float* __restrict__ outputs,
    const float4* __restrict__ tboxes,
    const int* __restrict__ tlabels,
    float* __restrict__ blocksums,
    int n)
{
    __shared__ float smem[IMGS * kImgF];   // 23520 B
    __shared__ float red[TPB / 64];
    const int tid = threadIdx.x;
    const int img0 = blockIdx.x * IMGS;
    const int nimg = min(IMGS, n - img0);

    float local = 0.0f;
    const float kno = 0.5f / (float)(2 * kCells);   // LAMBDA_NOOBJ / 98

    // ---- Prefetch this thread's target (overlaps the staging loads) ----
    const bool has_tgt = tid < nimg * kT;
    float4 tb = make_float4(0.f, 0.f, 0.f, 0.f);
    int lab = 0;
    if (has_tgt) {
        tb = tboxes[(size_t)img0 * kT + tid];
        lab = tlabels[(size_t)img0 * kT + tid];
    }

    // ---- Stage outputs into LDS, coalesced float4; noobj conf^2 from regs ----
    if (nimg == IMGS) {
        const float4* src = reinterpret_cast<const float4*>(outputs + (size_t)img0 * kImgF);
        float4* dst = reinterpret_cast<float4*>(smem);
        constexpr int NV4 = IMGS * kImgF / 4;       // 1470
        #pragma unroll
        for (int i = 0; i < (NV4 + TPB - 1) / TPB; i++) {
            const int idx = tid + i * TPB;
            if (idx < NV4) {
                const float4 v = src[idx];
                dst[idx] = v;
                // channel of v.x: (4*idx) % 30. Conf pair (ch 8,9) never
                // straddles a float4 (cell stride 30 == 2 mod 4).
                const int base = (4 * idx) % 30;
                if (base == 8)      local += kno * (v.x * v.x + v.y * v.y);
                else if (base == 6) local += kno * (v.z * v.z + v.w * v.w);
            }
        }
    } else {
        // tail (never hit at N=16384): scalar, correct but slow
        const float* srcf = outputs + (size_t)img0 * kImgF;
        const int tot = nimg * kImgF;
        for (int i = tid; i < tot; i += TPB) {
            const float v = srcf[i];
            smem[i] = v;
            const int ch = i % kCH;
            if (ch == 8 || ch == 9) local += kno * v * v;
        }
    }
    __syncthreads();

    // ---- per-target terms: thread tid -> target (tid&31) of image (tid>>5) ----
    if (has_tgt) {
        const int sub = tid >> 5;
        const float cellf = 1.0f / 7.0f;
        const float tx = tb.x, ty = tb.y, tw = tb.z, th = tb.w;

        int gxi = (int)(tx / cellf); gxi = min(max(gxi, 0), kS - 1);
        int gyi = (int)(ty / cellf); gyi = min(max(gyi, 0), kS - 1);
        const float ox = (tx - (float)gxi * cellf) / cellf;
        const float oy = (ty - (float)gyi * cellf) / cellf;
        const float* cellp = &smem[sub * kImgF + (gyi * kS + gxi) * kCH];

        const float t_x1 = tx - tw * 0.5f, t_x2 = tx + tw * 0.5f;
        const float t_y1 = ty - th * 0.5f, t_y2 = ty + th * 0.5f;
        const float tarea = tw * th;
        float ious[2], bxs[2], bys[2], bws[2], bhs[2];
        #pragma unroll
        for (int b = 0; b < 2; b++) {
            const float x = cellp[4 * b + 0], y = cellp[4 * b + 1];
            const float w = cellp[4 * b + 2], h = cellp[4 * b + 3];
            const float px = (x + (float)gxi) * cellf;
            const float py = (y + (float)gyi) * cellf;
            const float x21 = px - w * 0.5f, x22 = px + w * 0.5f;
            const float y21 = py - h * 0.5f, y22 = py + h * 0.5f;
            const float iw = fmaxf(fminf(t_x2, x22) - fmaxf(t_x1, x21), 0.0f);
            const float ih = fmaxf(fminf(t_y2, y22) - fmaxf(t_y1, y21), 0.0f);
            const float inter = iw * ih;
            const float uni = tarea + w * h - inter;
            ious[b] = inter / fmaxf(uni, 1e-6f);
            bxs[b] = px; bys[b] = py; bws[b] = w; bhs[b] = h;
        }
        // jnp.argmax picks the FIRST max on ties -> strict '>' for index 1
        const int best = (ious[1] > ious[0]) ? 1 : 0;

        const float pw = fmaxf(bws[best], 1e-6f), ph = fmaxf(bhs[best], 1e-6f);
        const float twc = fmaxf(tw, 1e-6f), thc = fmaxf(th, 1e-6f);
        const float dx = bxs[best] - ox, dy = bys[best] - oy;
        const float dw = sqrtf(pw) - sqrtf(twc), dh = sqrtf(ph) - sqrtf(thc);
        const float box_loss = dx * dx + dy * dy + dw * dw + dh * dh;

        const float dconf = cellp[8 + best] - 1.0f;
        const float obj_loss = dconf * dconf;

        // class loss: mean over C of (softmax - onehot)^2
        float m = cellp[10];
        #pragma unroll
        for (int c = 1; c < kC; c++) m = fmaxf(m, cellp[10 + c]);
        float es[kC];
        float ssum = 0.0f;
        #pragma unroll
        for (int c = 0; c < kC; c++) { es[c] = __expf(cellp[10 + c] - m); ssum += es[c]; }
        const float inv = 1.0f / ssum;
        float cl = 0.0f;
        #pragma unroll
        for (int c = 0; c < kC; c++) {
            const float d = es[c] * inv - (c == lab ? 1.0f : 0.0f);
            cl += d * d;
        }

        local += 5.0f * box_loss + obj_loss + cl * (1.0f / (float)kC);
    }

    const float bsum = block_reduce(local, red);
    if (tid == 0) blocksums[blockIdx.x] = bsum;
}

// Stage 2: reduce per-block partials, write mean.
__global__ __launch_bounds__(TPB) void yolo_stage2(
    const float* __restrict__ blocksums, int nblocks, float invn,
    float* __restrict__ out)
{
    __shared__ float red[TPB / 64];
    float local = 0.0f;
    for (int i = threadIdx.x; i < nblocks; i += TPB) local += blocksums[i];
    const float s = block_reduce(local, red);
    if (threadIdx.x == 0) out[0] = s * invn;
}

extern "C" void kernel_launch(void* const* d_in, const int* in_sizes, int n_in,
                              void* d_out, int out_size, void* d_ws, size_t ws_size,
                              hipStream_t stream)
{
    const float* outputs = (const float*)d_in[0];
    const float4* tboxes = (const float4*)d_in[1];
    const int* tlabels = (const int*)d_in[2];
    float* out = (float*)d_out;
    float* blocksums = (float*)d_ws;

    const int n = in_sizes[0] / kImgF;                 // 16384
    const int nblocks = (n + IMGS - 1) / IMGS;         // 4096

    yolo_stage1<<<nblocks, TPB, 0, stream>>>(outputs, tboxes, tlabels, blocksums, n);
    yolo_stage2<<<1, TPB, 0, stream>>>(blocksums, nblocks, 1.0f / (float)n, out);
}